// Round 3
// baseline (98.297 us; speedup 1.0000x reference)
//
#include <hip/hip_runtime.h>
#include <math.h>

// Problem constants (from reference)
#define B_    64
#define C_    8
#define T_    2048
#define K_    16
#define NF_   9
#define FEAT_ 144   // C_*NF_*2
#define MLP_  16
#define H1_   64
#define H2_   32
#define EFF_  60
#define W_    1988  // T_-EFF_
#define NCHK_ 32    // ceil(W_/64) w-chunks of 64
#define PI_F  3.14159265358979323846f

// Twiddles: angle(t) = 2*pi*t/16; f[n] = sum win[k]*exp(-i*2*pi*n*k/16)
constexpr float COS16[16] = {
   1.0f,  0.92387953251128674f,  0.70710678118654752f,  0.38268343236508977f,
   0.0f, -0.38268343236508977f, -0.70710678118654752f, -0.92387953251128674f,
  -1.0f, -0.92387953251128674f, -0.70710678118654752f, -0.38268343236508977f,
   0.0f,  0.38268343236508977f,  0.70710678118654752f,  0.92387953251128674f };
constexpr float SIN16F[16] = {
   0.0f,  0.38268343236508977f,  0.70710678118654752f,  0.92387953251128674f,
   1.0f,  0.92387953251128674f,  0.70710678118654752f,  0.38268343236508977f,
   0.0f, -0.38268343236508977f, -0.70710678118654752f, -0.92387953251128674f,
  -1.0f, -0.92387953251128674f, -0.70710678118654752f, -0.38268343236508977f };

// ---- fast device math (hw transcendentals) ----
__device__ __forceinline__ float fast_log1p(float s) {
  return __builtin_amdgcn_logf(1.0f + s) * 0.69314718055994531f;
}

__device__ __forceinline__ float atanpi_poly(float r) {
  const float s2 = r * r;
  float p = -0.0037310f;
  p = fmaf(p, s2,  0.0167600f);
  p = fmaf(p, s2, -0.0370617f);
  p = fmaf(p, s2,  0.0616068f);
  p = fmaf(p, s2, -0.10587734f);
  p = fmaf(p, s2,  0.31830265f);
  return r * p;
}

__device__ __forceinline__ float atan2pi_fast(float im, float re) {
  const float ax = fabsf(re), ay = fabsf(im);
  const float mx = fmaxf(ax, ay), mn = fminf(ax, ay);
  const float r = mn * __builtin_amdgcn_rcpf(fmaxf(mx, 1e-37f));
  float t = atanpi_poly(r);
  t = (ay > ax) ? 0.5f - t : t;
  t = (__float_as_uint(re) & 0x80000000u) ? 1.0f - t : t;  // signbit(re), handles -0
  return copysignf(t, im);                                  // im=+0 keeps +pi convention
}

__device__ __forceinline__ float fast_tanh(float z) {
  const float az = fabsf(z);
  const float e = __builtin_amdgcn_exp2f(-2.8853900817779268f * az);  // exp(-2|z|)
  const float th = fmaf(-2.0f, e * __builtin_amdgcn_rcpf(1.0f + e), 1.0f);
  return copysignf(th, z);
}

// ---------------- Kernel 0: transpose weights into workspace ----------------
__global__ __launch_bounds__(256) void prep_kernel(const float* __restrict__ pw,
                                                   const float* __restrict__ w2,
                                                   float* __restrict__ PWt,
                                                   float* __restrict__ W2t) {
  const int tid = blockIdx.x * 256 + threadIdx.x;
  if (tid < MLP_ * FEAT_) {
    const int j = tid / FEAT_, f = tid - j * FEAT_;  // pw[j][f]
    PWt[f * MLP_ + j] = pw[tid];
  }
  if (tid < H2_ * H1_) {
    const int m = tid >> 6, i = tid & 63;            // w2[m][i]
    W2t[i * H2_ + m] = w2[tid];
  }
}

// ---------------- Kernel 1: softmax weights over agg_w -> wts[W_] ----------------
__global__ __launch_bounds__(256) void softmax_kernel(const float* __restrict__ agg,
                                                      float* __restrict__ wts) {
  __shared__ float red[256];
  const int tid = threadIdx.x;
  float m = -INFINITY;
  for (int i = tid; i < W_; i += 256) m = fmaxf(m, agg[i]);
  red[tid] = m; __syncthreads();
  for (int s = 128; s > 0; s >>= 1) { if (tid < s) red[tid] = fmaxf(red[tid], red[tid+s]); __syncthreads(); }
  const float mx = red[0];
  __syncthreads();
  float sum = 0.f;
  for (int i = tid; i < W_; i += 256) sum += expf(agg[i] - mx);
  red[tid] = sum; __syncthreads();
  for (int s = 128; s > 0; s >>= 1) { if (tid < s) red[tid] += red[tid+s]; __syncthreads(); }
  const float inv = 1.f / red[0];
  for (int i = tid; i < W_; i += 256) wts[i] = expf(agg[i] - mx) * inv;
}

// ---------------- Kernel 2: fused, channel-split across 4 wave-groups ----------------
// block = 256 threads = 64 w-lanes x 4 groups (cg = wave id, wave-uniform).
// Each thread: DFT+proj for channels {cg, cg+4} -> pacc partial; LDS tree-reduce;
// all threads rebuild p; each cg computes 16 h1 rows + partial h2a; LDS tree-reduce;
// wave 0 finishes output head + weighted butterfly sum.
__global__ __launch_bounds__(256) void tcn_main(
    const float* __restrict__ x,
    const float* __restrict__ PWt, const float* __restrict__ proj_b,
    const float* __restrict__ w1, const float* __restrict__ b1,
    const float* __restrict__ W2t, const float* __restrict__ b2,
    const float* __restrict__ out_w, const float* __restrict__ out_b,
    const float* __restrict__ wts, float* __restrict__ partials) {
  __shared__ float buf[4096];   // 16 KiB, reused: [16][4][64] then [32][2][64]
  const int tid  = threadIdx.x;
  const int lane = tid & 63;
  const int cg   = tid >> 6;          // wave index, uniform per wave
  const int b     = blockIdx.y;
  const int chunk = blockIdx.x;
  const int w  = chunk * 64 + lane;
  const int wl = (w < W_) ? w : (W_ - 1);   // clamp; duplicates masked at the end

  // ---- stage 1: DFT + projection partial for channels cg, cg+4 ----
  float pacc[MLP_];
  #pragma unroll
  for (int j = 0; j < MLP_; j++) pacc[j] = 0.f;

  #pragma unroll
  for (int cc = 0; cc < 2; cc++) {
    const int c = cg + cc * 4;
    const float* xc = x + ((size_t)b * C_ + c) * T_ + wl;
    float win[K_];
    #pragma unroll
    for (int k = 0; k < K_; k++) win[k] = xc[k * 4];

    float ae[8], bo[8];
    #pragma unroll
    for (int k = 0; k < 8; k++) { ae[k] = win[k] + win[k+8]; bo[k] = win[k] - win[k+8]; }

    #pragma unroll
    for (int n = 0; n < NF_; n++) {
      float re = 0.f, im = 0.f;
      #pragma unroll
      for (int k = 0; k < 8; k++) {
        const float v = (n & 1) ? bo[k] : ae[k];
        const int t = (n * k) & 15;
        re = fmaf(v,  COS16[t],  re);
        im = fmaf(v, -SIN16F[t], im);   // im stays +0.0 exactly for n=0,8
      }
      const float s   = __builtin_amdgcn_sqrtf(fmaf(re, re, im * im));
      const float mag = fast_log1p(s);
      const float ph  = atan2pi_fast(im, re);
      const float* rm = PWt + (size_t)((c * NF_ + n) * 2) * MLP_;  // wave-uniform -> scalar loads
      #pragma unroll
      for (int j = 0; j < MLP_; j++)
        pacc[j] = fmaf(mag, rm[j], fmaf(ph, rm[MLP_ + j], pacc[j]));
    }
  }

  // ---- reduce pacc across the 4 groups: buf as [j][cg][lane] ----
  #pragma unroll
  for (int j = 0; j < MLP_; j++) buf[(j * 4 + cg) * 64 + lane] = pacc[j];
  __syncthreads();

  float p[MLP_];
  #pragma unroll
  for (int j = 0; j < MLP_; j++) {
    const float* r = &buf[j * 256];
    const float s01 = r[lane] + r[64 + lane];
    const float s23 = r[128 + lane] + r[192 + lane];
    p[j] = fast_tanh(s01 + s23 + proj_b[j]) * PI_F;
  }
  __syncthreads();  // buf reads done before reuse

  // ---- stage 3: each cg does 16 h1 rows, partial h2a[32] ----
  float h2a[H2_];
  #pragma unroll
  for (int m = 0; m < H2_; m++) h2a[m] = 0.f;

  #pragma unroll 4
  for (int ii = 0; ii < 16; ii++) {
    const int i = cg * 16 + ii;                 // wave-uniform row
    const float* r1 = w1 + i * MLP_;
    float acc = b1[i];
    #pragma unroll
    for (int j = 0; j < MLP_; j++) acc = fmaf(p[j], r1[j], acc);
    const float h1v = fmaxf(acc, 0.f);
    const float* r2 = W2t + i * H2_;
    #pragma unroll
    for (int m = 0; m < H2_; m++) h2a[m] = fmaf(h1v, r2[m], h2a[m]);
  }

  // ---- tree-reduce h2a: buf as [m][2][64] ----
  if (cg >= 2) {
    #pragma unroll
    for (int m = 0; m < H2_; m++) buf[(m * 2 + (cg - 2)) * 64 + lane] = h2a[m];
  }
  __syncthreads();
  if (cg < 2) {
    #pragma unroll
    for (int m = 0; m < H2_; m++) h2a[m] += buf[(m * 2 + cg) * 64 + lane];
  }
  __syncthreads();
  if (cg == 1) {
    #pragma unroll
    for (int m = 0; m < H2_; m++) buf[(m * 2) * 64 + lane] = h2a[m];
  }
  __syncthreads();

  if (cg == 0) {
    float o = out_b[0];
    #pragma unroll
    for (int m = 0; m < H2_; m++) {
      const float h2v = h2a[m] + buf[(m * 2) * 64 + lane] + b2[m];
      o = fmaf(fmaxf(h2v, 0.f), out_w[m], o);
    }
    float val = (w < W_) ? o * wts[wl] : 0.f;
    // deterministic butterfly over the 64 lanes of wave 0
    #pragma unroll
    for (int s = 32; s >= 1; s >>= 1) val += __shfl_xor(val, s, 64);
    if (lane == 0) partials[b * NCHK_ + chunk] = val;
  }
}

// ---------------- Kernel 3: fixed-order finalize ----------------
__global__ void finalize_kernel(const float* __restrict__ partials, float* __restrict__ out) {
  const int b = threadIdx.x;
  if (b < B_) {
    float s = 0.f;
    #pragma unroll
    for (int c = 0; c < NCHK_; c++) s += partials[b * NCHK_ + c];
    out[b] = s;
  }
}

extern "C" void kernel_launch(void* const* d_in, const int* in_sizes, int n_in,
                              void* d_out, int out_size, void* d_ws, size_t ws_size,
                              hipStream_t stream) {
  const float* x      = (const float*)d_in[0];
  const float* proj_w = (const float*)d_in[1];
  const float* proj_b = (const float*)d_in[2];
  const float* w1     = (const float*)d_in[3];
  const float* b1     = (const float*)d_in[4];
  const float* w2     = (const float*)d_in[5];
  const float* b2     = (const float*)d_in[6];
  const float* out_w  = (const float*)d_in[7];
  const float* out_b  = (const float*)d_in[8];
  const float* agg_w  = (const float*)d_in[9];

  float* wts      = (float*)d_ws;                    // W_ floats (2048 slot)
  float* partials = (float*)d_ws + 2048;             // B_*NCHK_ = 2048 floats
  float* PWt      = (float*)d_ws + 4096;             // FEAT_*MLP_ = 2304 floats
  float* W2t      = (float*)d_ws + 4096 + 2304;      // H1_*H2_ = 2048 floats

  prep_kernel<<<9, 256, 0, stream>>>(proj_w, w2, PWt, W2t);
  softmax_kernel<<<1, 256, 0, stream>>>(agg_w, wts);
  tcn_main<<<dim3(NCHK_, B_), 256, 0, stream>>>(x, PWt, proj_b, w1, b1, W2t, b2,
                                                out_w, out_b, wts, partials);
  finalize_kernel<<<1, 64, 0, stream>>>(partials, (float*)d_out);
}

// Round 4
// 68.527 us; speedup vs baseline: 1.4344x; 1.4344x over previous
//
#include <hip/hip_runtime.h>
#include <math.h>

// Problem constants (from reference)
#define B_    64
#define C_    8
#define T_    2048
#define K_    16
#define NF_   9
#define FEAT_ 144   // C_*NF_*2
#define MLP_  16
#define H1_   64
#define H2_   32
#define EFF_  60
#define W_    1988  // T_-EFF_
#define NWCH_ 8     // ceil(W_/256)
#define PI_F  3.14159265358979323846f

// Twiddles: angle(t) = 2*pi*t/16; f[n] = sum win[k]*exp(-i*2*pi*n*k/16)
constexpr float COS16[16] = {
   1.0f,  0.92387953251128674f,  0.70710678118654752f,  0.38268343236508977f,
   0.0f, -0.38268343236508977f, -0.70710678118654752f, -0.92387953251128674f,
  -1.0f, -0.92387953251128674f, -0.70710678118654752f, -0.38268343236508977f,
   0.0f,  0.38268343236508977f,  0.70710678118654752f,  0.92387953251128674f };
constexpr float SIN16F[16] = {
   0.0f,  0.38268343236508977f,  0.70710678118654752f,  0.92387953251128674f,
   1.0f,  0.92387953251128674f,  0.70710678118654752f,  0.38268343236508977f,
   0.0f, -0.38268343236508977f, -0.70710678118654752f, -0.92387953251128674f,
  -1.0f, -0.92387953251128674f, -0.70710678118654752f, -0.38268343236508977f };

// ---- fast device math (hw transcendentals) ----
__device__ __forceinline__ float fast_log1p(float s) {
  return __builtin_amdgcn_logf(1.0f + s) * 0.69314718055994531f;
}

__device__ __forceinline__ float atanpi_poly(float r) {
  const float s2 = r * r;
  float p = -0.0037310f;
  p = fmaf(p, s2,  0.0167600f);
  p = fmaf(p, s2, -0.0370617f);
  p = fmaf(p, s2,  0.0616068f);
  p = fmaf(p, s2, -0.10587734f);
  p = fmaf(p, s2,  0.31830265f);
  return r * p;
}

__device__ __forceinline__ float atan2pi_fast(float im, float re) {
  const float ax = fabsf(re), ay = fabsf(im);
  const float mx = fmaxf(ax, ay), mn = fminf(ax, ay);
  const float r = mn * __builtin_amdgcn_rcpf(fmaxf(mx, 1e-37f));
  float t = atanpi_poly(r);
  t = (ay > ax) ? 0.5f - t : t;
  t = (__float_as_uint(re) & 0x80000000u) ? 1.0f - t : t;  // signbit(re), handles -0
  return copysignf(t, im);                                  // im=+0 keeps +pi convention
}

__device__ __forceinline__ float fast_tanh(float z) {
  const float az = fabsf(z);
  const float e = __builtin_amdgcn_exp2f(-2.8853900817779268f * az);  // exp(-2|z|)
  const float th = fmaf(-2.0f, e * __builtin_amdgcn_rcpf(1.0f + e), 1.0f);
  return copysignf(th, z);
}

// ---------------- Kernel 0: fused setup (softmax + weight transposes) ----------------
__global__ __launch_bounds__(256) void setup_kernel(const float* __restrict__ agg,
                                                    float* __restrict__ wts,
                                                    const float* __restrict__ pw,
                                                    const float* __restrict__ w2,
                                                    float* __restrict__ PWt,
                                                    float* __restrict__ W2t) {
  if (blockIdx.x == 0) {
    __shared__ float red[256];
    const int tid = threadIdx.x;
    float m = -INFINITY;
    for (int i = tid; i < W_; i += 256) m = fmaxf(m, agg[i]);
    red[tid] = m; __syncthreads();
    for (int s = 128; s > 0; s >>= 1) { if (tid < s) red[tid] = fmaxf(red[tid], red[tid+s]); __syncthreads(); }
    const float mx = red[0];
    __syncthreads();
    float sum = 0.f;
    for (int i = tid; i < W_; i += 256) sum += expf(agg[i] - mx);
    red[tid] = sum; __syncthreads();
    for (int s = 128; s > 0; s >>= 1) { if (tid < s) red[tid] += red[tid+s]; __syncthreads(); }
    const float inv = 1.f / red[0];
    for (int i = tid; i < W_; i += 256) wts[i] = expf(agg[i] - mx) * inv;
  } else {
    const int tid = (blockIdx.x - 1) * 256 + threadIdx.x;
    if (tid < MLP_ * FEAT_) {
      const int j = tid / FEAT_, f = tid - j * FEAT_;  // pw[j][f]
      PWt[f * MLP_ + j] = pw[tid];
    }
    if (tid < H2_ * H1_) {
      const int m = tid >> 6, i = tid & 63;            // w2[m][i]
      W2t[i * H2_ + m] = w2[tid];
    }
  }
}

// ---------------- Kernel 1: fused DFT + feature + MLP + weighted partial sums ----------------
// One thread per (b,w). Stage-1 weights via wave-uniform scalar loads; stage-3 weights
// via LDS broadcast ds_read_b128 (parallel pipe to VALU). Channel loop unrolled x2 for
// load-latency overlap + independent transcendental chains.
__global__ __launch_bounds__(256) void tcn_main(
    const float* __restrict__ x,
    const float* __restrict__ PWt, const float* __restrict__ proj_b,
    const float* __restrict__ w1, const float* __restrict__ b1,
    const float* __restrict__ W2t, const float* __restrict__ b2,
    const float* __restrict__ out_w, const float* __restrict__ out_b,
    const float* __restrict__ wts, float* __restrict__ partials) {
  __shared__ __align__(16) float W1s[H1_ * MLP_];   // [i][j] as given
  __shared__ __align__(16) float W2s[H1_ * H2_];    // transposed [i][m]
  __shared__ float B1s[H1_];
  __shared__ float red[256];

  const int tid = threadIdx.x;
  for (int idx = tid; idx < H1_ * MLP_; idx += 256) W1s[idx] = w1[idx];
  for (int idx = tid; idx < H1_ * H2_; idx += 256) W2s[idx] = W2t[idx];
  if (tid < H1_) B1s[tid] = b1[tid];
  __syncthreads();

  const int b = blockIdx.y;
  const int w = blockIdx.x * 256 + tid;
  float val = 0.f;
  if (w < W_) {
    float pacc[MLP_];
    #pragma unroll
    for (int j = 0; j < MLP_; j++) pacc[j] = proj_b[j];

    const float* xb = x + (size_t)(b * C_) * T_ + w;
    #pragma unroll 1
    for (int cp = 0; cp < 4; cp++) {
      const float* xc0 = xb + (2 * cp) * T_;
      const float* xc1 = xb + (2 * cp + 1) * T_;
      float win0[K_], win1[K_];
      #pragma unroll
      for (int k = 0; k < K_; k++) win0[k] = xc0[k * 4];
      #pragma unroll
      for (int k = 0; k < K_; k++) win1[k] = xc1[k * 4];

      float ae0[8], bo0[8], ae1[8], bo1[8];
      #pragma unroll
      for (int k = 0; k < 8; k++) {
        ae0[k] = win0[k] + win0[k+8]; bo0[k] = win0[k] - win0[k+8];
        ae1[k] = win1[k] + win1[k+8]; bo1[k] = win1[k] - win1[k+8];
      }

      #pragma unroll
      for (int n = 0; n < NF_; n++) {
        float re0 = 0.f, im0 = 0.f, re1 = 0.f, im1 = 0.f;
        #pragma unroll
        for (int k = 0; k < 8; k++) {
          const int t = (n * k) & 15;
          const float cv = COS16[t], sv = -SIN16F[t];
          const float v0 = (n & 1) ? bo0[k] : ae0[k];
          const float v1 = (n & 1) ? bo1[k] : ae1[k];
          re0 = fmaf(v0, cv, re0); im0 = fmaf(v0, sv, im0);  // im stays +0.0 for n=0,8
          re1 = fmaf(v1, cv, re1); im1 = fmaf(v1, sv, im1);
        }
        const float s0   = __builtin_amdgcn_sqrtf(fmaf(re0, re0, im0 * im0));
        const float s1   = __builtin_amdgcn_sqrtf(fmaf(re1, re1, im1 * im1));
        const float mag0 = fast_log1p(s0);
        const float mag1 = fast_log1p(s1);
        const float ph0  = atan2pi_fast(im0, re0);
        const float ph1  = atan2pi_fast(im1, re1);

        const float* rm0 = PWt + (size_t)(((2*cp)   * NF_ + n) * 2) * MLP_;  // uniform -> s_load
        const float* rm1 = PWt + (size_t)(((2*cp+1) * NF_ + n) * 2) * MLP_;
        #pragma unroll
        for (int j = 0; j < MLP_; j++) {
          pacc[j] = fmaf(mag0, rm0[j], fmaf(ph0, rm0[MLP_ + j], pacc[j]));
          pacc[j] = fmaf(mag1, rm1[j], fmaf(ph1, rm1[MLP_ + j], pacc[j]));
        }
      }
    }

    float p[MLP_];
    #pragma unroll
    for (int j = 0; j < MLP_; j++) p[j] = fast_tanh(pacc[j]) * PI_F;

    float h2a[H2_];
    #pragma unroll
    for (int m = 0; m < H2_; m++) h2a[m] = b2[m];

    #pragma unroll 4
    for (int i = 0; i < H1_; i++) {
      const float4* r1 = reinterpret_cast<const float4*>(&W1s[i * MLP_]);  // LDS broadcast
      float acc = B1s[i];
      #pragma unroll
      for (int q = 0; q < 4; q++) {
        const float4 a = r1[q];
        acc = fmaf(p[4*q+0], a.x, acc);
        acc = fmaf(p[4*q+1], a.y, acc);
        acc = fmaf(p[4*q+2], a.z, acc);
        acc = fmaf(p[4*q+3], a.w, acc);
      }
      const float h1v = fmaxf(acc, 0.f);
      const float4* r2 = reinterpret_cast<const float4*>(&W2s[i * H2_]);   // LDS broadcast
      #pragma unroll
      for (int q = 0; q < 8; q++) {
        const float4 a = r2[q];
        h2a[4*q+0] = fmaf(h1v, a.x, h2a[4*q+0]);
        h2a[4*q+1] = fmaf(h1v, a.y, h2a[4*q+1]);
        h2a[4*q+2] = fmaf(h1v, a.z, h2a[4*q+2]);
        h2a[4*q+3] = fmaf(h1v, a.w, h2a[4*q+3]);
      }
    }

    float o = out_b[0];
    #pragma unroll
    for (int m = 0; m < H2_; m++) o = fmaf(fmaxf(h2a[m], 0.f), out_w[m], o);
    val = o * wts[w];
  }

  // deterministic block reduction
  red[tid] = val; __syncthreads();
  for (int s = 128; s > 0; s >>= 1) { if (tid < s) red[tid] += red[tid+s]; __syncthreads(); }
  if (tid == 0) partials[b * NWCH_ + blockIdx.x] = red[0];
}

// ---------------- Kernel 2: fixed-order finalize ----------------
__global__ void finalize_kernel(const float* __restrict__ partials, float* __restrict__ out) {
  const int b = threadIdx.x;
  if (b < B_) {
    float s = 0.f;
    #pragma unroll
    for (int c = 0; c < NWCH_; c++) s += partials[b * NWCH_ + c];
    out[b] = s;
  }
}

extern "C" void kernel_launch(void* const* d_in, const int* in_sizes, int n_in,
                              void* d_out, int out_size, void* d_ws, size_t ws_size,
                              hipStream_t stream) {
  const float* x      = (const float*)d_in[0];
  const float* proj_w = (const float*)d_in[1];
  const float* proj_b = (const float*)d_in[2];
  const float* w1     = (const float*)d_in[3];
  const float* b1     = (const float*)d_in[4];
  const float* w2     = (const float*)d_in[5];
  const float* b2     = (const float*)d_in[6];
  const float* out_w  = (const float*)d_in[7];
  const float* out_b  = (const float*)d_in[8];
  const float* agg_w  = (const float*)d_in[9];

  float* wts      = (float*)d_ws;                    // W_ floats (2048 slot)
  float* partials = (float*)d_ws + 2048;             // B_*NWCH_ floats
  float* PWt      = (float*)d_ws + 4096;             // FEAT_*MLP_ = 2304 floats
  float* W2t      = (float*)d_ws + 4096 + 2304;      // H1_*H2_ = 2048 floats

  setup_kernel<<<10, 256, 0, stream>>>(agg_w, wts, proj_w, w2, PWt, W2t);
  tcn_main<<<dim3(NWCH_, B_), 256, 0, stream>>>(x, PWt, proj_b, w1, b1, W2t, b2,
                                                out_w, out_b, wts, partials);
  finalize_kernel<<<1, 64, 0, stream>>>(partials, (float*)d_out);
}

// Round 5
// 64.850 us; speedup vs baseline: 1.5158x; 1.0567x over previous
//
#include <hip/hip_runtime.h>
#include <math.h>

// Problem constants (from reference)
#define B_    64
#define C_    8
#define T_    2048
#define K_    16
#define NF_   9
#define FEAT_ 144   // C_*NF_*2
#define MLP_  16
#define H1_   64
#define H2_   32
#define EFF_  60
#define W_    1988  // T_-EFF_
#define NWCH_ 8     // ceil(W_/256)
#define NG_   4     // channel groups (2 channels each)
#define PI_F  3.14159265358979323846f

// Twiddles: angle(t) = 2*pi*t/16; f[n] = sum win[k]*exp(-i*2*pi*n*k/16)
constexpr float COS16[16] = {
   1.0f,  0.92387953251128674f,  0.70710678118654752f,  0.38268343236508977f,
   0.0f, -0.38268343236508977f, -0.70710678118654752f, -0.92387953251128674f,
  -1.0f, -0.92387953251128674f, -0.70710678118654752f, -0.38268343236508977f,
   0.0f,  0.38268343236508977f,  0.70710678118654752f,  0.92387953251128674f };
constexpr float SIN16F[16] = {
   0.0f,  0.38268343236508977f,  0.70710678118654752f,  0.92387953251128674f,
   1.0f,  0.92387953251128674f,  0.70710678118654752f,  0.38268343236508977f,
   0.0f, -0.38268343236508977f, -0.70710678118654752f, -0.92387953251128674f,
  -1.0f, -0.92387953251128674f, -0.70710678118654752f, -0.38268343236508977f };

// ---- fast device math (hw transcendentals) ----
__device__ __forceinline__ float fast_log1p(float s) {
  return __builtin_amdgcn_logf(1.0f + s) * 0.69314718055994531f;
}

__device__ __forceinline__ float atanpi_poly(float r) {
  const float s2 = r * r;
  float p = -0.0037310f;
  p = fmaf(p, s2,  0.0167600f);
  p = fmaf(p, s2, -0.0370617f);
  p = fmaf(p, s2,  0.0616068f);
  p = fmaf(p, s2, -0.10587734f);
  p = fmaf(p, s2,  0.31830265f);
  return r * p;
}

__device__ __forceinline__ float atan2pi_fast(float im, float re) {
  const float ax = fabsf(re), ay = fabsf(im);
  const float mx = fmaxf(ax, ay), mn = fminf(ax, ay);
  const float r = mn * __builtin_amdgcn_rcpf(fmaxf(mx, 1e-37f));
  float t = atanpi_poly(r);
  t = (ay > ax) ? 0.5f - t : t;
  t = (__float_as_uint(re) & 0x80000000u) ? 1.0f - t : t;  // signbit(re), handles -0
  return copysignf(t, im);                                  // im=+0 keeps +pi convention
}

__device__ __forceinline__ float fast_tanh(float z) {
  const float az = fabsf(z);
  const float e = __builtin_amdgcn_exp2f(-2.8853900817779268f * az);  // exp(-2|z|)
  const float th = fmaf(-2.0f, e * __builtin_amdgcn_rcpf(1.0f + e), 1.0f);
  return copysignf(th, z);
}

// DFT + feature + projection partial for ONE channel, accumulated into pacc.
__device__ __forceinline__ void dft_proj_channel(const float* __restrict__ xc,
                                                 const float* __restrict__ PWt,
                                                 int c, float* pacc) {
  float win[K_];
  #pragma unroll
  for (int k = 0; k < K_; k++) win[k] = xc[k * 4];
  float ae[8], bo[8];
  #pragma unroll
  for (int k = 0; k < 8; k++) { ae[k] = win[k] + win[k+8]; bo[k] = win[k] - win[k+8]; }
  #pragma unroll
  for (int n = 0; n < NF_; n++) {
    float re = 0.f, im = 0.f;
    #pragma unroll
    for (int k = 0; k < 8; k++) {
      const float v = (n & 1) ? bo[k] : ae[k];
      const int t = (n * k) & 15;
      re = fmaf(v,  COS16[t],  re);
      im = fmaf(v, -SIN16F[t], im);   // im stays +0.0 exactly for n=0,8
    }
    const float s   = __builtin_amdgcn_sqrtf(fmaf(re, re, im * im));
    const float mag = fast_log1p(s);
    const float ph  = atan2pi_fast(im, re);
    const float* rm = PWt + (size_t)((c * NF_ + n) * 2) * MLP_;  // wave-uniform -> s_load
    #pragma unroll
    for (int j = 0; j < MLP_; j++)
      pacc[j] = fmaf(mag, rm[j], fmaf(ph, rm[MLP_ + j], pacc[j]));
  }
}

// MLP tail: p[16] -> weighted output value (weights via wave-uniform scalar loads).
__device__ __forceinline__ float mlp_tail(const float* p,
                                          const float* __restrict__ w1, const float* __restrict__ b1,
                                          const float* __restrict__ W2t, const float* __restrict__ b2,
                                          const float* __restrict__ out_w, const float* __restrict__ out_b) {
  float h2a[H2_];
  #pragma unroll
  for (int m = 0; m < H2_; m++) h2a[m] = b2[m];
  #pragma unroll 8
  for (int i = 0; i < H1_; i++) {
    const float* r1 = w1 + i * MLP_;
    float acc = b1[i];
    #pragma unroll
    for (int j = 0; j < MLP_; j++) acc = fmaf(p[j], r1[j], acc);
    const float h1v = fmaxf(acc, 0.f);
    const float* r2 = W2t + i * H2_;
    #pragma unroll
    for (int m = 0; m < H2_; m++) h2a[m] = fmaf(h1v, r2[m], h2a[m]);
  }
  float o = out_b[0];
  #pragma unroll
  for (int m = 0; m < H2_; m++) o = fmaf(fmaxf(h2a[m], 0.f), out_w[m], o);
  return o;
}

// ---------------- Kernel 0: fused setup (softmax + weight transposes) ----------------
__global__ __launch_bounds__(256) void setup_kernel(const float* __restrict__ agg,
                                                    float* __restrict__ wts,
                                                    const float* __restrict__ pw,
                                                    const float* __restrict__ w2,
                                                    float* __restrict__ PWt,
                                                    float* __restrict__ W2t) {
  if (blockIdx.x == 0) {
    __shared__ float red[256];
    const int tid = threadIdx.x;
    float m = -INFINITY;
    for (int i = tid; i < W_; i += 256) m = fmaxf(m, agg[i]);
    red[tid] = m; __syncthreads();
    for (int s = 128; s > 0; s >>= 1) { if (tid < s) red[tid] = fmaxf(red[tid], red[tid+s]); __syncthreads(); }
    const float mx = red[0];
    __syncthreads();
    float sum = 0.f;
    for (int i = tid; i < W_; i += 256) sum += expf(agg[i] - mx);
    red[tid] = sum; __syncthreads();
    for (int s = 128; s > 0; s >>= 1) { if (tid < s) red[tid] += red[tid+s]; __syncthreads(); }
    const float inv = 1.f / red[0];
    for (int i = tid; i < W_; i += 256) wts[i] = expf(agg[i] - mx) * inv;
  } else {
    const int tid = (blockIdx.x - 1) * 256 + threadIdx.x;
    if (tid < MLP_ * FEAT_) {
      const int j = tid / FEAT_, f = tid - j * FEAT_;  // pw[j][f]
      PWt[f * MLP_ + j] = pw[tid];
    }
    if (tid < H2_ * H1_) {
      const int m = tid >> 6, i = tid & 63;            // w2[m][i]
      W2t[i * H2_ + m] = w2[tid];
    }
  }
}

// ---------------- Split path: stage 1 (4x parallelism) ----------------
// grid (NWCH_, B_, NG_); each thread: 2 channels -> partial pacc[16] -> pf.
__global__ __launch_bounds__(256) void tcn_stage1(const float* __restrict__ x,
                                                  const float* __restrict__ PWt,
                                                  float* __restrict__ pf) {
  const int tid = threadIdx.x;
  const int b = blockIdx.y, g = blockIdx.z;
  const int w = blockIdx.x * 256 + tid;
  if (w >= W_) return;
  float pacc[MLP_];
  #pragma unroll
  for (int j = 0; j < MLP_; j++) pacc[j] = 0.f;
  #pragma unroll 1
  for (int cc = 0; cc < 2; cc++) {
    const int c = g * 2 + cc;
    dft_proj_channel(x + ((size_t)b * C_ + c) * T_ + w, PWt, c, pacc);
  }
  float4* dst = reinterpret_cast<float4*>(pf + ((size_t)(b * NG_ + g) * W_ + w) * MLP_);
  #pragma unroll
  for (int q = 0; q < 4; q++)
    dst[q] = make_float4(pacc[4*q+0], pacc[4*q+1], pacc[4*q+2], pacc[4*q+3]);
}

// ---------------- Split path: stage 2 (tail) ----------------
__global__ __launch_bounds__(256) void tcn_stage2(const float* __restrict__ pf,
                                                  const float* __restrict__ proj_b,
                                                  const float* __restrict__ w1, const float* __restrict__ b1,
                                                  const float* __restrict__ W2t, const float* __restrict__ b2,
                                                  const float* __restrict__ out_w, const float* __restrict__ out_b,
                                                  const float* __restrict__ wts, float* __restrict__ partials) {
  __shared__ float red[256];
  const int tid = threadIdx.x;
  const int b = blockIdx.y;
  const int w = blockIdx.x * 256 + tid;
  float val = 0.f;
  if (w < W_) {
    float pacc[MLP_];
    #pragma unroll
    for (int j = 0; j < MLP_; j++) pacc[j] = proj_b[j];
    #pragma unroll
    for (int g = 0; g < NG_; g++) {           // fixed order -> deterministic
      const float4* src = reinterpret_cast<const float4*>(pf + ((size_t)(b * NG_ + g) * W_ + w) * MLP_);
      #pragma unroll
      for (int q = 0; q < 4; q++) {
        const float4 a = src[q];
        pacc[4*q+0] += a.x; pacc[4*q+1] += a.y; pacc[4*q+2] += a.z; pacc[4*q+3] += a.w;
      }
    }
    float p[MLP_];
    #pragma unroll
    for (int j = 0; j < MLP_; j++) p[j] = fast_tanh(pacc[j]) * PI_F;
    val = mlp_tail(p, w1, b1, W2t, b2, out_w, out_b) * wts[w];
  }
  red[tid] = val; __syncthreads();
  for (int s = 128; s > 0; s >>= 1) { if (tid < s) red[tid] += red[tid+s]; __syncthreads(); }
  if (tid == 0) partials[b * NWCH_ + blockIdx.x] = red[0];
}

// ---------------- Fallback: proven monolithic kernel (R2 structure) ----------------
__global__ __launch_bounds__(256) void tcn_mono(const float* __restrict__ x,
                                                const float* __restrict__ PWt, const float* __restrict__ proj_b,
                                                const float* __restrict__ w1, const float* __restrict__ b1,
                                                const float* __restrict__ W2t, const float* __restrict__ b2,
                                                const float* __restrict__ out_w, const float* __restrict__ out_b,
                                                const float* __restrict__ wts, float* __restrict__ partials) {
  __shared__ float red[256];
  const int tid = threadIdx.x;
  const int b = blockIdx.y;
  const int w = blockIdx.x * 256 + tid;
  float val = 0.f;
  if (w < W_) {
    float pacc[MLP_];
    #pragma unroll
    for (int j = 0; j < MLP_; j++) pacc[j] = proj_b[j];
    #pragma unroll 1
    for (int c = 0; c < C_; c++)
      dft_proj_channel(x + ((size_t)b * C_ + c) * T_ + w, PWt, c, pacc);
    float p[MLP_];
    #pragma unroll
    for (int j = 0; j < MLP_; j++) p[j] = fast_tanh(pacc[j]) * PI_F;
    val = mlp_tail(p, w1, b1, W2t, b2, out_w, out_b) * wts[w];
  }
  red[tid] = val; __syncthreads();
  for (int s = 128; s > 0; s >>= 1) { if (tid < s) red[tid] += red[tid+s]; __syncthreads(); }
  if (tid == 0) partials[b * NWCH_ + blockIdx.x] = red[0];
}

// ---------------- finalize ----------------
__global__ void finalize_kernel(const float* __restrict__ partials, float* __restrict__ out) {
  const int b = threadIdx.x;
  if (b < B_) {
    float s = 0.f;
    #pragma unroll
    for (int c = 0; c < NWCH_; c++) s += partials[b * NWCH_ + c];
    out[b] = s;
  }
}

extern "C" void kernel_launch(void* const* d_in, const int* in_sizes, int n_in,
                              void* d_out, int out_size, void* d_ws, size_t ws_size,
                              hipStream_t stream) {
  const float* x      = (const float*)d_in[0];
  const float* proj_w = (const float*)d_in[1];
  const float* proj_b = (const float*)d_in[2];
  const float* w1     = (const float*)d_in[3];
  const float* b1     = (const float*)d_in[4];
  const float* w2     = (const float*)d_in[5];
  const float* b2     = (const float*)d_in[6];
  const float* out_w  = (const float*)d_in[7];
  const float* out_b  = (const float*)d_in[8];
  const float* agg_w  = (const float*)d_in[9];

  float* wts      = (float*)d_ws;                    // W_ floats (2048 slot)
  float* partials = (float*)d_ws + 2048;             // B_*NWCH_ floats
  float* PWt      = (float*)d_ws + 4096;             // FEAT_*MLP_ = 2304 floats
  float* W2t      = (float*)d_ws + 4096 + 2304;      // H1_*H2_ = 2048 floats
  float* pf       = (float*)d_ws + 16384;            // B_*NG_*W_*MLP_ floats

  const size_t need = ((size_t)16384 + (size_t)B_ * NG_ * W_ * MLP_) * sizeof(float);

  setup_kernel<<<10, 256, 0, stream>>>(agg_w, wts, proj_w, w2, PWt, W2t);
  if (ws_size >= need) {
    tcn_stage1<<<dim3(NWCH_, B_, NG_), 256, 0, stream>>>(x, PWt, pf);
    tcn_stage2<<<dim3(NWCH_, B_), 256, 0, stream>>>(pf, proj_b, w1, b1, W2t, b2,
                                                    out_w, out_b, wts, partials);
  } else {
    tcn_mono<<<dim3(NWCH_, B_), 256, 0, stream>>>(x, PWt, proj_b, w1, b1, W2t, b2,
                                                  out_w, out_b, wts, partials);
  }
  finalize_kernel<<<1, 64, 0, stream>>>(partials, (float*)d_out);
}